// Round 14
// baseline (191.248 us; speedup 1.0000x reference)
//
#include <hip/hip_runtime.h>
#include <hip/hip_bf16.h>

#define BATCH  128
#define WIDTH  8192
#define DIM    64
#define FILT   32
#define KSZ    3
#define WOUT   8190

// 512 blocks (2/CU), 512 threads; 4 blocks per batch sample
#define NW     8
#define RPW    16     // output rows per wave per step
#define WT     128    // rows per block-step; 4*16*128 = 8192 >= 8190
#define TPB    16     // steps per block
#define NBX    4
#define XR     130    // 128 rows + 2 halo rows (wave 7 stages a half-DMA extra)

typedef __attribute__((ext_vector_type(8))) _Float16 f16x8;
typedef __attribute__((ext_vector_type(4))) float f32x4;
typedef __attribute__((ext_vector_type(4))) unsigned u32x4;

__global__ void zero_cnt(unsigned* cnt) {
  cnt[threadIdx.x] = 0u;   // 128 per-batch arrival counters, reset every call
}

// Fused kernel. Phase 1: conv into hold[16][4] packed-f16 registers, block
// min/max -> mm (agent release) + per-batch soft barrier (4 blocks).
// Phase 2: normalize from registers -> out. Intermediate never touches HBM.
__global__ __launch_bounds__(512, 4)
void conv_norm(const float* __restrict__ x, const float* __restrict__ ker,
               float* __restrict__ out, float* __restrict__ mm,
               unsigned* __restrict__ cnt)
{
  // SHARED double-buffered tile: 130 rows x 64 f32. Content swizzled:
  // xs[bb][row][slot16] = x[row][slot16 ^ (row&7)]. Rows 0..127 staged by
  // waves 0..7 (16 rows each); halo rows 128,129 by wave 7's 5th half-DMA.
  // Cross-wave reads are protected by the per-step s_barrier.
  __shared__ __align__(16) float xs[2][XR * DIM];      // 66,560 B
  __shared__ __align__(16) short ks[KSZ * FILT * DIM]; // 12,288 B
  __shared__ float red[2 * NW];

  const int t  = threadIdx.x;
  const int l  = t & 63;
  const int wv = t >> 6;
  const int b  = blockIdx.x >> 2;
  const int bx = blockIdx.x & 3;
  const int step0 = bx * TPB;
  const float* xb = x + (long)b * WIDTH * DIM;

  // Per-wave stage into the SHARED buffer region [wv*16, wv*16+16); wave 7
  // additionally stages halo rows 128,129 with a 32-lane half-DMA.
  auto stage = [&](int bb, int step) {
    long gw0 = (long)(step0 + step) * WT + wv * RPW;
    char* lb = (char*)&xs[bb][0] + wv * (RPW * DIM * 4);
    #pragma unroll
    for (int j = 0; j < 4; ++j) {
      int row_l = j * 4 + (l >> 4);          // buffer row = wv*16+row_l; &7 == row_l&7
      int slot  = (l & 15) ^ (row_l & 7);
      long gr = gw0 + row_l;
      if (gr > WIDTH - 1) gr = WIDTH - 1;    // edge clamp (feeds masked outputs only)
      __builtin_amdgcn_global_load_lds(
          (const __attribute__((address_space(1))) void*)(xb + gr * DIM + slot * 4),
          (__attribute__((address_space(3))) void*)(lb + j * 1024), 16, 0, 0);
    }
    if (wv == 7 && l < 32) {                 // halo rows 128,129 (512 B)
      int row_l = 16 + (l >> 4);             // 16,17 -> buffer rows 128,129
      int slot  = (l & 15) ^ (row_l & 7);
      long gr = gw0 + row_l;
      if (gr > WIDTH - 1) gr = WIDTH - 1;
      __builtin_amdgcn_global_load_lds(
          (const __attribute__((address_space(1))) void*)(xb + gr * DIM + slot * 4),
          (__attribute__((address_space(3))) void*)(lb + 4 * 1024), 16, 0, 0);
    }
  };

  stage(0, 0);   // prologue prefetch; hides under weight staging

  // weights: fp32 [k][d][f] coalesced -> f16 LDS [k][f][d]; swizzle (f>>1)&7
  // spreads same-parity filter rows (the per-MFMA B-read set) over 8 bank-quads.
  #pragma unroll
  for (int i = 0; i < 12; ++i) {
    int idx = t + i * 512;
    int k = idx >> 11, rem = idx & 2047;
    int d = rem >> 5,  f = rem & 31;
    _Float16 hv = (_Float16)ker[idx];
    int byte = ((k * FILT + f) * DIM + d) * 2;
    byte ^= ((f >> 1) & 7) << 4;
    ks[byte >> 1] = __builtin_bit_cast(short, hv);
  }
  __syncthreads();   // full drain: weights + ALL waves' step-0 DMAs

  unsigned hold[TPB][4];                 // 64 VGPR of packed f16 conv outputs
  float mx = -INFINITY, mn = INFINITY;
  int kso = 0;                           // CSE/LICM blur for per-step B reads
  int cur = 0;

  #pragma unroll
  for (int it = 0; it < TPB; ++it) {
    if (it + 1 < TPB) stage(cur ^ 1, it + 1);   // next tile flies during compute
    asm volatile("" : "+v"(kso));

    const float* xl = &xs[cur][0];
    f32x4 acc0 = (f32x4){0.f, 0.f, 0.f, 0.f};
    f32x4 acc1 = (f32x4){0.f, 0.f, 0.f, 0.f};

    #pragma unroll
    for (int s = 0; s < KSZ; ++s) {
      #pragma unroll
      for (int kh = 0; kh < 2; ++kh) {
        int ra = wv * RPW + (l & 15) + s;   // up to 129: halo, staged + barriered
        int sg = kh * 8 + (l >> 4) * 2;
        int rb = ra & 7;
        f32x4 u0 = *reinterpret_cast<const f32x4*>(&xl[ra * DIM + ((sg    ) ^ rb) * 4]);
        f32x4 u1 = *reinterpret_cast<const f32x4*>(&xl[ra * DIM + ((sg + 1) ^ rb) * 4]);
        u32x4 pk;
        pk.x = __builtin_bit_cast(unsigned, __builtin_amdgcn_cvt_pkrtz(u0.x, u0.y));
        pk.y = __builtin_bit_cast(unsigned, __builtin_amdgcn_cvt_pkrtz(u0.z, u0.w));
        pk.z = __builtin_bit_cast(unsigned, __builtin_amdgcn_cvt_pkrtz(u1.x, u1.y));
        pk.w = __builtin_bit_cast(unsigned, __builtin_amdgcn_cvt_pkrtz(u1.z, u1.w));
        f16x8 av = __builtin_bit_cast(f16x8, pk);

        int d0 = kh * 32 + (l >> 4) * 8;
        int f0 = 2 * (l & 15);
        int byteA = ((s * FILT + f0) * DIM + d0) * 2;
        byteA ^= ((f0 >> 1) & 7) << 4;
        int byteB = ((s * FILT + f0 + 1) * DIM + d0) * 2;
        byteB ^= (((f0 + 1) >> 1) & 7) << 4;
        f16x8 B0 = *reinterpret_cast<const f16x8*>(&ks[(byteA >> 1) + kso]);
        f16x8 B1 = *reinterpret_cast<const f16x8*>(&ks[(byteB >> 1) + kso]);

        acc0 = __builtin_amdgcn_mfma_f32_16x16x32_f16(av, B0, acc0, 0, 0, 0);
        acc1 = __builtin_amdgcn_mfma_f32_16x16x32_f16(av, B1, acc1, 0, 0, 0);
      }
    }

    long gw0 = (long)(step0 + it) * WT + wv * RPW;
    #pragma unroll
    for (int r = 0; r < 4; ++r) {
      int wl = (l >> 4) * 4 + r;           // C-row = (lane>>4)*4+reg; all 16 valid
      long gr = gw0 + wl;
      float v0 = acc0[r], v1 = acc1[r];    // filters 2*(l&15), 2*(l&15)+1
      if (gr < WOUT) {
        mx = fmaxf(mx, fmaxf(v0, v1));
        mn = fminf(mn, fminf(v0, v1));
      }
      hold[it][r] = __builtin_bit_cast(unsigned, __builtin_amdgcn_cvt_pkrtz(v0, v1));
    }

    // End-of-step: own next-buffer DMAs complete + own LDS reads consumed,
    // then block-wide rendezvous. After this barrier every wave's stage of
    // cur^1 is complete and every wave is done reading cur.
    if (it + 1 < TPB) {
      asm volatile("s_waitcnt vmcnt(0) lgkmcnt(0)" ::: "memory");
      asm volatile("s_barrier" ::: "memory");
      __builtin_amdgcn_sched_barrier(0);
    }
    cur ^= 1;
  }

  // ---- block min/max -> mm, then per-batch soft barrier (4 blocks)
  #pragma unroll
  for (int off = 32; off > 0; off >>= 1) {
    mx = fmaxf(mx, __shfl_down(mx, off));
    mn = fminf(mn, __shfl_down(mn, off));
  }
  if (l == 0) { red[wv * 2] = mx; red[wv * 2 + 1] = mn; }
  __syncthreads();
  if (t == 0) {
    float Mx = -INFINITY, Mn = INFINITY;
    #pragma unroll
    for (int w = 0; w < NW; ++w) {
      Mx = fmaxf(Mx, red[w * 2]);
      Mn = fminf(Mn, red[w * 2 + 1]);
    }
    __hip_atomic_store(&mm[(b * NBX + bx) * 2],     Mx,
                       __ATOMIC_RELEASE, __HIP_MEMORY_SCOPE_AGENT);
    __hip_atomic_store(&mm[(b * NBX + bx) * 2 + 1], Mn,
                       __ATOMIC_RELEASE, __HIP_MEMORY_SCOPE_AGENT);
    __hip_atomic_fetch_add(&cnt[b], 1u, __ATOMIC_ACQ_REL, __HIP_MEMORY_SCOPE_AGENT);
    while (__hip_atomic_load(&cnt[b], __ATOMIC_ACQUIRE, __HIP_MEMORY_SCOPE_AGENT) < 4u)
      __builtin_amdgcn_s_sleep(2);
    float GMx = -INFINITY, GMn = INFINITY;
    #pragma unroll
    for (int i = 0; i < NBX; ++i) {
      GMx = fmaxf(GMx, __hip_atomic_load(&mm[(b * NBX + i) * 2],
                                         __ATOMIC_ACQUIRE, __HIP_MEMORY_SCOPE_AGENT));
      GMn = fminf(GMn, __hip_atomic_load(&mm[(b * NBX + i) * 2 + 1],
                                         __ATOMIC_ACQUIRE, __HIP_MEMORY_SCOPE_AGENT));
    }
    red[0] = GMx; red[1] = GMn;
  }
  __syncthreads();

  // ---- phase 2: normalize from registers, store out
  const float Mn = red[1];
  const float rs = 1.0f / (red[0] - Mn);

  #pragma unroll
  for (int it = 0; it < TPB; ++it) {
    long gw0 = (long)(step0 + it) * WT + wv * RPW;
    #pragma unroll
    for (int r = 0; r < 4; ++r) {
      int wl = (l >> 4) * 4 + r;
      long gr = gw0 + wl;
      if (gr < WOUT) {
        unsigned u = hold[it][r];
        float v0 = (float)__builtin_bit_cast(_Float16, (unsigned short)(u & 0xffffu));
        float v1 = (float)__builtin_bit_cast(_Float16, (unsigned short)(u >> 16));
        float2 o;
        o.x = (v0 - Mn) * rs;
        o.y = (v1 - Mn) * rs;
        *reinterpret_cast<float2*>(out + ((long)b * WOUT + gr) * FILT + 2 * (l & 15)) = o;
      }
    }
  }
}

extern "C" void kernel_launch(void* const* d_in, const int* in_sizes, int n_in,
                              void* d_out, int out_size, void* d_ws, size_t ws_size,
                              hipStream_t stream) {
  const float* x   = (const float*)d_in[0];
  const float* ker = (const float*)d_in[1];
  float* out = (float*)d_out;
  float*    mm  = (float*)d_ws;                      // 1024 floats (4 KB)
  unsigned* cnt = (unsigned*)((char*)d_ws + 4096);   // 128 arrival counters

  zero_cnt<<<dim3(1), dim3(128), 0, stream>>>(cnt);
  conv_norm<<<dim3(NBX * BATCH), dim3(512), 0, stream>>>(x, ker, out, mm, cnt);
}